// Round 10
// baseline (3102.235 us; speedup 1.0000x reference)
//
#include <hip/hip_runtime.h>

typedef __bf16 bf16x8 __attribute__((ext_vector_type(8)));
typedef unsigned short us8 __attribute__((ext_vector_type(8)));
typedef float f32x4 __attribute__((ext_vector_type(4)));

#define NROW 32      // rows per workgroup (160 WGs x 32 = 5120)
#define A_STR 136    // ushort stride per h row: 17 dword-quads ≡ 1 mod 8 -> balanced b128
#define AX_STR 40    // ushort stride per Ax row
#define WL_STR 521   // 16B-units per frag-row of LDS Whh0 half (521 ≡ 1 mod 8)
#define NSTEP 119

__device__ __forceinline__ unsigned short f2bf(float f){
  unsigned int x = __builtin_bit_cast(unsigned int, f);
  x += 0x7fffu + ((x >> 16) & 1u);          // RNE
  return (unsigned short)(x >> 16);
}
__device__ __forceinline__ float bf2f(unsigned short s){
  unsigned int x = ((unsigned int)s) << 16;
  return __builtin_bit_cast(float, x);
}
__device__ __forceinline__ float sigm(float x){ return 1.0f/(1.0f + __expf(-x)); }
__device__ __forceinline__ float tanh_(float x){ float e = __expf(2.0f*x); return 1.0f - 2.0f/(e + 1.0f); }

__device__ __forceinline__ f32x4 MFMA(us8 a, us8 b, f32x4 c){
  return __builtin_amdgcn_mfma_f32_16x16x32_bf16(
      __builtin_bit_cast(bf16x8, a), __builtin_bit_cast(bf16x8, b), c, 0, 0, 0);
}
// AGPR-pinned weight MFMA (v7/v8-proven: weight array cannot spill)
__device__ __forceinline__ void mfma_ag_first(f32x4& d, us8 a, us8 b){
  asm("s_nop 1\n\tv_mfma_f32_16x16x32_bf16 %0, %1, %2, %0" : "+v"(d) : "v"(a), "a"(b));
}
__device__ __forceinline__ void mfma_ag(f32x4& d, us8 a, us8 b){
  asm("v_mfma_f32_16x16x32_bf16 %0, %1, %2, %0" : "+v"(d) : "v"(a), "a"(b));
}
__device__ __forceinline__ void accfence4(f32x4& a0, f32x4& a1, f32x4& a2, f32x4& a3){
  asm("s_nop 7\n\ts_nop 7\n\ts_nop 2"
      : "+v"(a0), "+v"(a1), "+v"(a2), "+v"(a3));
}

struct SharedMem {
  unsigned short A0[2][NROW*A_STR];     // h0 bf16, double buffered  (17408 B)
  unsigned short A1[2][NROW*A_STR];     // h1 bf16, double buffered  (17408 B)
  unsigned short Ax[2][NROW][AX_STR];   // x-MFMA A operand           (5120 B)
  unsigned short xw[512*8];             // x-MFMA B per gate-col      (8192 B)
  unsigned short W0l[8*WL_STR*8];       // Whh0 k-blocks 0,1 frags   (66688 B)
  float b1[512];                        //                            (2048 B)
  float Wh2f[256];                      //                            (1024 B)
  float we_s[64];
  float be_s[64];
  float bh_s[2];
};  // ~116 KB -> 1 WG/CU; no c_lds, no red (regs / shfl now)

// 512 threads = 8 waves = 2/SIMD. Budget: 128 arch + 128 AGPR.
// AGPR: Wih1(16 frags) + Whh1(16 frags) = 128 exact. Arch: WV 32 + acc 32 + c 16 + misc.
__global__ __launch_bounds__(512)
__attribute__((amdgpu_waves_per_eu(2, 2)))
void deepar_kernel(
    const float* __restrict__ hist, const float* __restrict__ fut,
    const float* __restrict__ We,   const float* __restrict__ be,
    const float* __restrict__ Wih0, const float* __restrict__ Whh0,
    const float* __restrict__ bih0, const float* __restrict__ bhh0,
    const float* __restrict__ Wih1, const float* __restrict__ Whh1,
    const float* __restrict__ bih1, const float* __restrict__ bhh1,
    const float* __restrict__ Wh,   const float* __restrict__ bh,
    float* __restrict__ out)
{
  __shared__ SharedMem S;
  const int tid = threadIdx.x;     // 0..511
  const int wg  = blockIdx.x;
  const int b   = wg / 10;
  const int n0  = (wg % 10) * NROW;
  const int l   = tid & 63;
  const int w   = tid >> 6;        // wave 0..7
  const int gq  = l >> 4;          // k-group 0..3
  const int r   = l & 15;          // row/col within 16-tile
  const int cw  = w * 16;          // h-col base of this wave (gate-aligned 64 gate-cols)

  // ---------------- prologue ----------------
  {
    us8 z = {0,0,0,0,0,0,0,0};
    us8* pA0 = (us8*)&S.A0[0][0];
    us8* pA1 = (us8*)&S.A1[0][0];
    for (int i = tid; i < 2*NROW*A_STR/8; i += 512){ pA0[i] = z; pA1[i] = z; }
    us8* pAx = (us8*)&S.Ax[0][0][0];
    for (int i = tid; i < 2*NROW*AX_STR/8; i += 512) pAx[i] = z;
  }
  if (tid < 64)       S.we_s[tid]       = We[tid];
  else if (tid < 128) S.be_s[tid - 64]  = be[tid - 64];
  else if (tid < 384) S.Wh2f[tid - 128] = Wh[tid - 128];
  else if (tid < 386) S.bh_s[tid - 384] = bh[tid - 384];
  __syncthreads();

  // per-col x weights: u = Wih0[:,:64]@We ; v = ..@be + bih0 + bhh0
  {
    const float* wr = Wih0 + tid * 68;
    float u = 0.f, v = 0.f;
    #pragma unroll 8
    for (int e = 0; e < 64; ++e){
      float wv = wr[e];
      u = fmaf(wv, S.we_s[e], u);
      v = fmaf(wv, S.be_s[e], v);
    }
    v += bih0[tid] + bhh0[tid];
    unsigned short* xp = &S.xw[tid * 8];
    xp[0] = f2bf(u);
    xp[1] = f2bf(wr[64]); xp[2] = f2bf(wr[65]); xp[3] = f2bf(wr[66]); xp[4] = f2bf(wr[67]);
    xp[5] = f2bf(v);
    xp[6] = 0; xp[7] = 0;
    S.b1[tid] = bih1[tid] + bhh1[tid];
  }
  // Whh0 k-blocks 0,1 -> LDS frags
  for (int idx = tid; idx < 8*512; idx += 512){
    int qgq = idx >> 9, col = idx & 511;
    const float* p = Whh0 + col*128 + qgq*8;
    f32x4 x0 = *(const f32x4*)p;
    f32x4 x1 = *(const f32x4*)(p + 4);
    us8 tt;
    tt[0]=f2bf(x0[0]); tt[1]=f2bf(x0[1]); tt[2]=f2bf(x0[2]); tt[3]=f2bf(x0[3]);
    tt[4]=f2bf(x1[0]); tt[5]=f2bf(x1[1]); tt[6]=f2bf(x1[2]); tt[7]=f2bf(x1[3]);
    *(us8*)&S.W0l[(qgq*WL_STR + col)*8] = tt;
  }
  // Ax constant-one column (k=5), both buffers
  if (tid < 64){ int row = tid >> 1, bsel = tid & 1; S.Ax[bsel][row][5] = 0x3F80; }
  // stage step-0 scalars
  if (tid < 160){
    int srow, sch, tau;
    if (tid < 32){ srow = tid; sch = 0; tau = 0; }
    else { int k = tid - 32; srow = k >> 2; sch = 1 + (k & 3); tau = 1; }
    const float* p = hist + ((b*96 + tau)*320 + n0 + srow)*5;
    S.Ax[0][srow][sch] = f2bf(p[sch]);
  }

  // register weights (per wave, cols g*128+cw+r):
  //   WV  (arch):  Whh0 k2,k3  8 frags = 32 regs
  //   WA1 (AGPR):  Wih1 all k 16 frags = 64 regs
  //   WA2 (AGPR):  Whh1 all k 16 frags = 64 regs
  us8 WV[4][2], WA1[4][4], WA2[4][4];
  #pragma unroll
  for (int m = 0; m < 3; ++m){
    const float* base = (m == 0) ? Whh0 : (m == 1) ? Wih1 : Whh1;
    #pragma unroll
    for (int g = 0; g < 4; ++g){
      int col = g*128 + cw + r;
      #pragma unroll
      for (int q = 0; q < 4; ++q){
        if (m == 0 && q < 2) continue;
        const float* p = base + col*128 + q*32 + gq*8;
        f32x4 x0 = *(const f32x4*)p;
        f32x4 x1 = *(const f32x4*)(p + 4);
        us8 tt;
        tt[0]=f2bf(x0[0]); tt[1]=f2bf(x0[1]); tt[2]=f2bf(x0[2]); tt[3]=f2bf(x0[3]);
        tt[4]=f2bf(x1[0]); tt[5]=f2bf(x1[1]); tt[6]=f2bf(x1[2]); tt[7]=f2bf(x1[3]);
        if (m == 0)      WV[g][q-2] = tt;
        else if (m == 1) WA1[g][q]  = tt;
        else             WA2[g][q]  = tt;
      }
    }
  }

  __syncthreads();

  float b1g[4];
  #pragma unroll
  for (int g = 0; g < 4; ++g) b1g[g] = S.b1[g*128 + cw + r];
  const float bh0 = S.bh_s[0], bh1 = S.bh_s[1];

  f32x4 c0s[2], c1s[2];
  #pragma unroll
  for (int rt = 0; rt < 2; ++rt){
    f32x4 z = {0.f,0.f,0.f,0.f};
    c0s[rt] = z; c1s[rt] = z;
  }

  // head helper (barrier-free: shfl-xor reduce over cg, lane cg==0 stores)
  auto head_op = [&](const unsigned short* A1h, int hs){
    const int rown = tid >> 4, cg = tid & 15;
    us8 hv = *(const us8*)&A1h[rown*A_STR + cg*8];
    f32x4 wA0v = *(const f32x4*)&S.Wh2f[cg*8];
    f32x4 wA1v = *(const f32x4*)&S.Wh2f[cg*8 + 4];
    f32x4 wB0v = *(const f32x4*)&S.Wh2f[128 + cg*8];
    f32x4 wB1v = *(const f32x4*)&S.Wh2f[128 + cg*8 + 4];
    float pm = 0.f, ps = 0.f;
    #pragma unroll
    for (int k = 0; k < 4; ++k){
      float h0v = bf2f(hv[k]);     h0v = h0v > 0.f ? h0v : 0.f;
      float h1v = bf2f(hv[4 + k]); h1v = h1v > 0.f ? h1v : 0.f;
      pm = fmaf(h0v, wA0v[k], pm);  pm = fmaf(h1v, wA1v[k], pm);
      ps = fmaf(h0v, wB0v[k], ps);  ps = fmaf(h1v, wB1v[k], ps);
    }
    #pragma unroll
    for (int m = 1; m < 16; m <<= 1){
      pm += __shfl_xor(pm, m, 64);
      ps += __shfl_xor(ps, m, 64);
    }
    if (cg == 0){
      float mu = pm + bh0;
      float sg = ps + bh1;
      sg = (sg > 15.f) ? sg : __logf(1.0f + __expf(sg));
      float2 o2 = make_float2(mu, sg);
      *(float2*)&out[((b*24 + (hs - 95))*320 + (n0 + rown))*2] = o2;
    }
  };

  // ---- phase 0: layer0(0) = x-part only (h0(-1)=0) ----
  {
    float stv = 0.f; int sto = -1;
    if (tid < 160){
      int srow, sch, tau;
      if (tid < 32){ srow = tid; sch = 0; tau = 1; }
      else { int k = tid - 32; srow = k >> 2; sch = 1 + (k & 3); tau = 2; }
      const float* p = hist + ((b*96 + tau)*320 + n0 + srow)*5;
      stv = p[sch];
      sto = 1*NROW*AX_STR + srow*AX_STR + sch;
    }
    unsigned short* A0w = S.A0[0];
    #pragma unroll
    for (int rt = 0; rt < 2; ++rt){
      const int rbase = rt * 16;
      f32x4 acc[4];
      us8 ax = *(const us8*)&S.Ax[0][rbase + r][gq*8];
      #pragma unroll
      for (int g = 0; g < 4; ++g){
        us8 bx = *(const us8*)&S.xw[(g*128 + cw + r)*8];
        f32x4 z = {0.f,0.f,0.f,0.f};
        acc[g] = MFMA(ax, bx, z);
      }
      f32x4 cn;
      #pragma unroll
      for (int j = 0; j < 4; ++j){
        float c = fmaf(sigm(acc[1][j]), c0s[rt][j], sigm(acc[0][j]) * tanh_(acc[2][j]));
        cn[j] = c;
        float h = sigm(acc[3][j]) * tanh_(c);
        A0w[(rbase + gq*4 + j)*A_STR + cw + r] = f2bf(h);
      }
      c0s[rt] = cn;
    }
    if (sto >= 0) ((unsigned short*)&S.Ax[0][0][0])[sto] = f2bf(stv);
    __syncthreads();
  }

  // ---- main phases p = 1..119: layer1(p-1) || layer0(p) ----
  for (int p = 1; p <= NSTEP; ++p){
    const int pa = p & 1, pm1 = pa ^ 1;
    const unsigned short* A0p = S.A0[pm1];   // h0(p-1): input to BOTH layers
    unsigned short*       A0w = S.A0[pa];    // h0(p)
    const unsigned short* A1p = S.A1[pa];    // h1(p-2)
    unsigned short*       A1w = S.A1[pm1];   // h1(p-1)
    const bool doL0 = (p <= NSTEP - 1);

    // prefetch scalars for step p+1 into Ax[(p+1)&1]
    float stv = 0.f; int sto = -1;
    if (p <= NSTEP - 2 && tid < 160){
      int srow, sch, tau;
      if (tid < 32){ srow = tid; sch = 0; tau = p + 1; }
      else { int k = tid - 32; srow = k >> 2; sch = 1 + (k & 3); tau = p + 2; }
      const float* ptr = (tau < 96) ? (hist + ((b*96 + tau)*320 + n0 + srow)*5)
                                    : (fut  + ((b*24 + (tau - 96))*320 + n0 + srow)*5);
      stv = ptr[sch];
      sto = pm1*NROW*AX_STR + srow*AX_STR + sch;
    }

    // head for step p-2 (h1(p-2) = A1p, synced last phase)
    if (p >= 97) head_op(A1p, p - 2);

    #pragma unroll
    for (int rt = 0; rt < 2; ++rt){
      const int rbase = rt * 16;
      f32x4 aL1[4], aL0[4];
      #pragma unroll
      for (int g = 0; g < 4; ++g){
        f32x4 iv = {b1g[g], b1g[g], b1g[g], b1g[g]};
        aL1[g] = iv;
      }
      if (doL0){
        us8 ax = *(const us8*)&S.Ax[pa][rbase + r][gq*8];
        #pragma unroll
        for (int g = 0; g < 4; ++g){
          us8 bx = *(const us8*)&S.xw[(g*128 + cw + r)*8];
          f32x4 z = {0.f,0.f,0.f,0.f};
          aL0[g] = MFMA(ax, bx, z);
        }
      }
      // shared A0(p-1) fragment loop: feeds Wih1 (layer1) AND Whh0 (layer0)
      #pragma unroll
      for (int q = 0; q < 4; ++q){
        us8 a = *(const us8*)&A0p[(rbase + r)*A_STR + q*32 + gq*8];
        if (q == 0){
          mfma_ag_first(aL1[0], a, WA1[0][0]);
          mfma_ag(aL1[1], a, WA1[1][0]);
          mfma_ag(aL1[2], a, WA1[2][0]);
          mfma_ag(aL1[3], a, WA1[3][0]);
        } else {
          #pragma unroll
          for (int g = 0; g < 4; ++g) mfma_ag(aL1[g], a, WA1[g][q]);
        }
        if (doL0){
          if (q < 2){
            #pragma unroll
            for (int g = 0; g < 4; ++g){
              us8 bw = *(const us8*)&S.W0l[((q*4 + gq)*WL_STR + g*128 + cw + r)*8];
              aL0[g] = MFMA(a, bw, aL0[g]);
            }
          } else {
            #pragma unroll
            for (int g = 0; g < 4; ++g) aL0[g] = MFMA(a, WV[g][q-2], aL0[g]);
          }
        }
      }
      // layer1 recurrent part: h1(p-2) @ Whh1^T
      #pragma unroll
      for (int q = 0; q < 4; ++q){
        us8 a1 = *(const us8*)&A1p[(rbase + r)*A_STR + q*32 + gq*8];
        #pragma unroll
        for (int g = 0; g < 4; ++g) mfma_ag(aL1[g], a1, WA2[g][q]);
      }
      accfence4(aL1[0], aL1[1], aL1[2], aL1[3]);
      {
        f32x4 cn;
        #pragma unroll
        for (int j = 0; j < 4; ++j){
          float c = fmaf(sigm(aL1[1][j]), c1s[rt][j], sigm(aL1[0][j]) * tanh_(aL1[2][j]));
          cn[j] = c;
          float h = sigm(aL1[3][j]) * tanh_(c);
          A1w[(rbase + gq*4 + j)*A_STR + cw + r] = f2bf(h);
        }
        c1s[rt] = cn;
      }
      if (doL0){
        f32x4 cn;
        #pragma unroll
        for (int j = 0; j < 4; ++j){
          float c = fmaf(sigm(aL0[1][j]), c0s[rt][j], sigm(aL0[0][j]) * tanh_(aL0[2][j]));
          cn[j] = c;
          float h = sigm(aL0[3][j]) * tanh_(c);
          A0w[(rbase + gq*4 + j)*A_STR + cw + r] = f2bf(h);
        }
        c0s[rt] = cn;
      }
    }
    if (sto >= 0) ((unsigned short*)&S.Ax[0][0][0])[sto] = f2bf(stv);
    __syncthreads();
  }

  // ---- final head: step 118, h1 in A1[(NSTEP-1)&1] = A1[0] ----
  head_op(S.A1[0], NSTEP - 1);
}

extern "C" void kernel_launch(void* const* d_in, const int* in_sizes, int n_in,
                              void* d_out, int out_size, void* d_ws, size_t ws_size,
                              hipStream_t stream) {
  const float* hist = (const float*)d_in[0];
  const float* fut  = (const float*)d_in[1];
  const float* We   = (const float*)d_in[2];
  const float* be   = (const float*)d_in[3];
  const float* Wih0 = (const float*)d_in[4];
  const float* Whh0 = (const float*)d_in[5];
  const float* bih0 = (const float*)d_in[6];
  const float* bhh0 = (const float*)d_in[7];
  const float* Wih1 = (const float*)d_in[8];
  const float* Whh1 = (const float*)d_in[9];
  const float* bih1 = (const float*)d_in[10];
  const float* bhh1 = (const float*)d_in[11];
  const float* Wh   = (const float*)d_in[12];
  const float* bh   = (const float*)d_in[13];
  float* out = (float*)d_out;

  deepar_kernel<<<dim3(160), dim3(512), 0, stream>>>(
      hist, fut, We, be, Wih0, Whh0, bih0, bhh0,
      Wih1, Whh1, bih1, bhh1, Wh, bh, out);
}

// Round 11
// 1290.609 us; speedup vs baseline: 2.4037x; 2.4037x over previous
//
#include <hip/hip_runtime.h>

typedef __bf16 bf16x8 __attribute__((ext_vector_type(8)));
typedef unsigned short us8 __attribute__((ext_vector_type(8)));
typedef float f32x4 __attribute__((ext_vector_type(4)));

#define NROW 32      // rows per workgroup (160 WGs x 32 = 5120)
#define A_STR 136    // ushort stride per h row
#define AX_STR 40    // ushort stride per Ax row
#define WL_STR 521   // 16B-units per frag-row of LDS Whh0 half
#define NSTEP 119

__device__ __forceinline__ unsigned short f2bf(float f){
  unsigned int x = __builtin_bit_cast(unsigned int, f);
  x += 0x7fffu + ((x >> 16) & 1u);          // RNE
  return (unsigned short)(x >> 16);
}
__device__ __forceinline__ float bf2f(unsigned short s){
  unsigned int x = ((unsigned int)s) << 16;
  return __builtin_bit_cast(float, x);
}
__device__ __forceinline__ float sigm(float x){ return 1.0f/(1.0f + __expf(-x)); }
__device__ __forceinline__ float tanh_(float x){ float e = __expf(2.0f*x); return 1.0f - 2.0f/(e + 1.0f); }

__device__ __forceinline__ f32x4 MFMA(us8 a, us8 b, f32x4 c){
  return __builtin_amdgcn_mfma_f32_16x16x32_bf16(
      __builtin_bit_cast(bf16x8, a), __builtin_bit_cast(bf16x8, b), c, 0, 0, 0);
}
// AGPR-pinned weight MFMA: "a" forces the weight's home into the AGPR half of
// the unified file, so the arch half stays under budget (no accvgpr thrash).
__device__ __forceinline__ void mfma_ag_first(f32x4& d, us8 a, us8 b){
  asm("s_nop 1\n\tv_mfma_f32_16x16x32_bf16 %0, %1, %2, %0" : "+v"(d) : "v"(a), "a"(b));
}
__device__ __forceinline__ void mfma_ag(f32x4& d, us8 a, us8 b){
  asm("v_mfma_f32_16x16x32_bf16 %0, %1, %2, %0" : "+v"(d) : "v"(a), "a"(b));
}
__device__ __forceinline__ void accfence4(f32x4& a0, f32x4& a1, f32x4& a2, f32x4& a3){
  asm("s_nop 7\n\ts_nop 7\n\ts_nop 2"
      : "+v"(a0), "+v"(a1), "+v"(a2), "+v"(a3));
}

struct SharedMem {
  unsigned short A0[2][NROW*A_STR];     // h0 bf16, double buffered  (17408 B)
  unsigned short A1[2][NROW*A_STR];     // h1 bf16, double buffered  (17408 B)
  unsigned short Ax[2][NROW][AX_STR];   // x-MFMA A operand           (5120 B)
  unsigned short xw[512*8];             // x-MFMA B per gate-col      (8192 B)
  unsigned short W0l[8*WL_STR*8];       // Whh0 k-blocks 0,1 frags   (66688 B)
  float c_lds[2][2][512][4];            // c[layer][rt][tid][j]      (32768 B)
  float b1[512];                        //                            (2048 B)
  float Wh2f[256];                      //                            (1024 B)
  float we_s[64];
  float be_s[64];
  float bh_s[2];
};  // ~151 KB -> 1 WG/CU

// 512 threads = 8 waves = 2/SIMD. Unified budget 256/wave.
// AGPR 160 (ALL weights: Whh0-k23 32 + Wih1 64 + Whh1 64); arch ~96.
__global__ __launch_bounds__(512)
__attribute__((amdgpu_waves_per_eu(2, 2)))
void deepar_kernel(
    const float* __restrict__ hist, const float* __restrict__ fut,
    const float* __restrict__ We,   const float* __restrict__ be,
    const float* __restrict__ Wih0, const float* __restrict__ Whh0,
    const float* __restrict__ bih0, const float* __restrict__ bhh0,
    const float* __restrict__ Wih1, const float* __restrict__ Whh1,
    const float* __restrict__ bih1, const float* __restrict__ bhh1,
    const float* __restrict__ Wh,   const float* __restrict__ bh,
    float* __restrict__ out)
{
  __shared__ SharedMem S;
  const int tid = threadIdx.x;     // 0..511
  const int wg  = blockIdx.x;
  const int b   = wg / 10;
  const int n0  = (wg % 10) * NROW;
  const int l   = tid & 63;
  const int w   = tid >> 6;        // wave 0..7
  const int gq  = l >> 4;          // k-group 0..3
  const int r   = l & 15;          // row/col within 16-tile
  const int cw  = w * 16;          // h-col base of this wave

  // ---------------- prologue ----------------
  {
    us8 z = {0,0,0,0,0,0,0,0};
    us8* pA0 = (us8*)&S.A0[0][0];
    us8* pA1 = (us8*)&S.A1[0][0];
    for (int i = tid; i < 2*NROW*A_STR/8; i += 512){ pA0[i] = z; pA1[i] = z; }
    us8* pAx = (us8*)&S.Ax[0][0][0];
    for (int i = tid; i < 2*NROW*AX_STR/8; i += 512) pAx[i] = z;
    f32x4 zf = {0.f,0.f,0.f,0.f};
    #pragma unroll
    for (int q = 0; q < 4; ++q) *(f32x4*)&S.c_lds[q >> 1][q & 1][tid][0] = zf;
  }
  if (tid < 64)       S.we_s[tid]       = We[tid];
  else if (tid < 128) S.be_s[tid - 64]  = be[tid - 64];
  else if (tid < 384) S.Wh2f[tid - 128] = Wh[tid - 128];
  else if (tid < 386) S.bh_s[tid - 384] = bh[tid - 384];
  __syncthreads();

  // per-col x weights: u = Wih0[:,:64]@We ; v = ..@be + bih0 + bhh0
  {
    const float* wr = Wih0 + tid * 68;
    float u = 0.f, v = 0.f;
    #pragma unroll 8
    for (int e = 0; e < 64; ++e){
      float wv = wr[e];
      u = fmaf(wv, S.we_s[e], u);
      v = fmaf(wv, S.be_s[e], v);
    }
    v += bih0[tid] + bhh0[tid];
    unsigned short* xp = &S.xw[tid * 8];
    xp[0] = f2bf(u);
    xp[1] = f2bf(wr[64]); xp[2] = f2bf(wr[65]); xp[3] = f2bf(wr[66]); xp[4] = f2bf(wr[67]);
    xp[5] = f2bf(v);
    xp[6] = 0; xp[7] = 0;
    S.b1[tid] = bih1[tid] + bhh1[tid];
  }
  // Whh0 k-blocks 0,1 -> LDS frags
  for (int idx = tid; idx < 8*512; idx += 512){
    int qgq = idx >> 9, col = idx & 511;
    const float* p = Whh0 + col*128 + qgq*8;
    f32x4 x0 = *(const f32x4*)p;
    f32x4 x1 = *(const f32x4*)(p + 4);
    us8 tt;
    tt[0]=f2bf(x0[0]); tt[1]=f2bf(x0[1]); tt[2]=f2bf(x0[2]); tt[3]=f2bf(x0[3]);
    tt[4]=f2bf(x1[0]); tt[5]=f2bf(x1[1]); tt[6]=f2bf(x1[2]); tt[7]=f2bf(x1[3]);
    *(us8*)&S.W0l[(qgq*WL_STR + col)*8] = tt;
  }
  // Ax constant-one column (k=5), both buffers
  if (tid < 64){ int row = tid >> 1, bsel = tid & 1; S.Ax[bsel][row][5] = 0x3F80; }
  // stage step-0 scalars
  if (tid < 160){
    int srow, sch, tau;
    if (tid < 32){ srow = tid; sch = 0; tau = 0; }
    else { int k = tid - 32; srow = k >> 2; sch = 1 + (k & 3); tau = 1; }
    const float* p = hist + ((b*96 + tau)*320 + n0 + srow)*5;
    S.Ax[0][srow][sch] = f2bf(p[sch]);
  }

  // ALL weight fragments -> AGPR (asm-pinned):
  //   WA0: Whh0 k2,k3  [g][q-2]  8 frags = 32 AGPR
  //   WA1: Wih1 all k  [g][q]   16 frags = 64 AGPR
  //   WA2: Whh1 all k  [g][q]   16 frags = 64 AGPR
  us8 WA0[4][2], WA1[4][4], WA2[4][4];
  #pragma unroll
  for (int m = 0; m < 3; ++m){
    const float* base = (m == 0) ? Whh0 : (m == 1) ? Wih1 : Whh1;
    #pragma unroll
    for (int g = 0; g < 4; ++g){
      int col = g*128 + cw + r;
      #pragma unroll
      for (int q = 0; q < 4; ++q){
        if (m == 0 && q < 2) continue;
        const float* p = base + col*128 + q*32 + gq*8;
        f32x4 x0 = *(const f32x4*)p;
        f32x4 x1 = *(const f32x4*)(p + 4);
        us8 tt;
        tt[0]=f2bf(x0[0]); tt[1]=f2bf(x0[1]); tt[2]=f2bf(x0[2]); tt[3]=f2bf(x0[3]);
        tt[4]=f2bf(x1[0]); tt[5]=f2bf(x1[1]); tt[6]=f2bf(x1[2]); tt[7]=f2bf(x1[7-7]); // placeholder fixed below
        tt[4]=f2bf(x1[0]); tt[5]=f2bf(x1[1]); tt[6]=f2bf(x1[2]); tt[7]=f2bf(x1[3]);
        if (m == 0)      WA0[g][q-2] = tt;
        else if (m == 1) WA1[g][q]  = tt;
        else             WA2[g][q]  = tt;
      }
    }
  }

  __syncthreads();

  float b1g[4];
  #pragma unroll
  for (int g = 0; g < 4; ++g) b1g[g] = S.b1[g*128 + cw + r];
  const float bh0 = S.bh_s[0], bh1 = S.bh_s[1];

  // ---------------- time loop ----------------
  for (int t = 0; t < NSTEP; ++t){
    const int pb = t & 1, nb = pb ^ 1;
    const unsigned short* A0r = S.A0[pb];
    unsigned short*       A0w = S.A0[nb];
    const unsigned short* A1r = S.A1[pb];
    unsigned short*       A1w = S.A1[nb];

    // prefetch next-step scalars (latency hidden under both layers)
    float stv = 0.f; int sto = -1;
    if (t + 1 < NSTEP && tid < 160){
      int srow, sch, tau;
      if (tid < 32){ srow = tid; sch = 0; tau = t + 1; }
      else { int k = tid - 32; srow = k >> 2; sch = 1 + (k & 3); tau = t + 2; }
      const float* p = (tau < 96) ? (hist + ((b*96 + tau)*320 + n0 + srow)*5)
                                  : (fut  + ((b*24 + (tau - 96))*320 + n0 + srow)*5);
      stv = p[sch];
      sto = nb*NROW*AX_STR + srow*AX_STR + sch;
    }

    // ---- layer 0: gates = x-MFMA + h0 @ Whh0^T (k0,k1 LDS; k2,k3 AGPR) ----
    #pragma unroll
    for (int rt = 0; rt < 2; ++rt){
      const int rbase = rt * 16;
      f32x4 cprev = *(const f32x4*)&S.c_lds[0][rt][tid][0];   // hoisted early
      f32x4 acc[4];
      us8 ax = *(const us8*)&S.Ax[pb][rbase + r][gq*8];
      #pragma unroll
      for (int g = 0; g < 4; ++g){
        us8 bx = *(const us8*)&S.xw[(g*128 + cw + r)*8];
        f32x4 z = {0.f,0.f,0.f,0.f};
        acc[g] = MFMA(ax, bx, z);
      }
      #pragma unroll
      for (int q = 0; q < 2; ++q){
        us8 a = *(const us8*)&A0r[(rbase + r)*A_STR + q*32 + gq*8];
        #pragma unroll
        for (int g = 0; g < 4; ++g){
          us8 bw = *(const us8*)&S.W0l[((q*4 + gq)*WL_STR + g*128 + cw + r)*8];
          acc[g] = MFMA(a, bw, acc[g]);
        }
      }
      #pragma unroll
      for (int q = 2; q < 4; ++q){
        us8 a = *(const us8*)&A0r[(rbase + r)*A_STR + q*32 + gq*8];
        #pragma unroll
        for (int g = 0; g < 4; ++g) mfma_ag(acc[g], a, WA0[g][q-2]);
      }
      accfence4(acc[0], acc[1], acc[2], acc[3]);
      f32x4 cnew;
      #pragma unroll
      for (int j = 0; j < 4; ++j){
        float c = fmaf(sigm(acc[1][j]), cprev[j], sigm(acc[0][j]) * tanh_(acc[2][j]));
        cnew[j] = c;
        float h = sigm(acc[3][j]) * tanh_(c);
        A0w[(rbase + gq*4 + j)*A_STR + cw + r] = f2bf(h);
      }
      *(f32x4*)&S.c_lds[0][rt][tid][0] = cnew;
    }
    __syncthreads();   // B1: new h0 visible

    // ---- layer 1: gates = b1 + h0new @ Wih1^T + h1 @ Whh1^T (all AGPR) ----
    #pragma unroll
    for (int rt = 0; rt < 2; ++rt){
      const int rbase = rt * 16;
      f32x4 cprev = *(const f32x4*)&S.c_lds[1][rt][tid][0];   // hoisted early
      f32x4 acc[4];
      #pragma unroll
      for (int g = 0; g < 4; ++g){
        f32x4 iv = {b1g[g], b1g[g], b1g[g], b1g[g]};
        acc[g] = iv;
      }
      {
        us8 a = *(const us8*)&A0w[(rbase + r)*A_STR + 0*32 + gq*8];
        mfma_ag_first(acc[0], a, WA1[0][0]);
        mfma_ag(acc[1], a, WA1[1][0]);
        mfma_ag(acc[2], a, WA1[2][0]);
        mfma_ag(acc[3], a, WA1[3][0]);
      }
      #pragma unroll
      for (int q = 1; q < 4; ++q){
        us8 a = *(const us8*)&A0w[(rbase + r)*A_STR + q*32 + gq*8];
        #pragma unroll
        for (int g = 0; g < 4; ++g) mfma_ag(acc[g], a, WA1[g][q]);
      }
      #pragma unroll
      for (int q = 0; q < 4; ++q){
        us8 a = *(const us8*)&A1r[(rbase + r)*A_STR + q*32 + gq*8];
        #pragma unroll
        for (int g = 0; g < 4; ++g) mfma_ag(acc[g], a, WA2[g][q]);
      }
      accfence4(acc[0], acc[1], acc[2], acc[3]);
      f32x4 cnew;
      #pragma unroll
      for (int j = 0; j < 4; ++j){
        float c = fmaf(sigm(acc[1][j]), cprev[j], sigm(acc[0][j]) * tanh_(acc[2][j]));
        cnew[j] = c;
        float h = sigm(acc[3][j]) * tanh_(c);
        A1w[(rbase + gq*4 + j)*A_STR + cw + r] = f2bf(h);
      }
      *(f32x4*)&S.c_lds[1][rt][tid][0] = cnew;
    }
    if (sto >= 0) ((unsigned short*)&S.Ax[0][0][0])[sto] = f2bf(stv);
    __syncthreads();   // B2: new h1 + next-step Ax visible

    // ---- head (last 24 steps): barrier-free shfl-xor reduce ----
    if (t >= 95){
      const int rown = tid >> 4, cg = tid & 15;
      us8 hv = *(const us8*)&A1w[rown*A_STR + cg*8];
      f32x4 wA0v = *(const f32x4*)&S.Wh2f[cg*8];
      f32x4 wA1v = *(const f32x4*)&S.Wh2f[cg*8 + 4];
      f32x4 wB0v = *(const f32x4*)&S.Wh2f[128 + cg*8];
      f32x4 wB1v = *(const f32x4*)&S.Wh2f[128 + cg*8 + 4];
      float pm = 0.f, ps = 0.f;
      #pragma unroll
      for (int k = 0; k < 4; ++k){
        float h0v = bf2f(hv[k]);     h0v = h0v > 0.f ? h0v : 0.f;
        float h1v = bf2f(hv[4 + k]); h1v = h1v > 0.f ? h1v : 0.f;
        pm = fmaf(h0v, wA0v[k], pm);  pm = fmaf(h1v, wA1v[k], pm);
        ps = fmaf(h0v, wB0v[k], ps);  ps = fmaf(h1v, wB1v[k], ps);
      }
      #pragma unroll
      for (int m = 1; m < 16; m <<= 1){
        pm += __shfl_xor(pm, m, 64);
        ps += __shfl_xor(ps, m, 64);
      }
      if (cg == 0){
        float mu = pm + bh0;
        float sg = ps + bh1;
        sg = (sg > 15.f) ? sg : __logf(1.0f + __expf(sg));
        float2 o2 = make_float2(mu, sg);
        *(float2*)&out[((b*24 + (t - 95))*320 + (n0 + rown))*2] = o2;
      }
    }
  }
}

extern "C" void kernel_launch(void* const* d_in, const int* in_sizes, int n_in,
                              void* d_out, int out_size, void* d_ws, size_t ws_size,
                              hipStream_t stream) {
  const float* hist = (const float*)d_in[0];
  const float* fut  = (const float*)d_in[1];
  const float* We   = (const float*)d_in[2];
  const float* be   = (const float*)d_in[3];
  const float* Wih0 = (const float*)d_in[4];
  const float* Whh0 = (const float*)d_in[5];
  const float* bih0 = (const float*)d_in[6];
  const float* bhh0 = (const float*)d_in[7];
  const float* Wih1 = (const float*)d_in[8];
  const float* Whh1 = (const float*)d_in[9];
  const float* bih1 = (const float*)d_in[10];
  const float* bhh1 = (const float*)d_in[11];
  const float* Wh   = (const float*)d_in[12];
  const float* bh   = (const float*)d_in[13];
  float* out = (float*)d_out;

  deepar_kernel<<<dim3(160), dim3(512), 0, stream>>>(
      hist, fut, We, be, Wih0, Whh0, bih0, bhh0,
      Wih1, Whh1, bih1, bhh1, Wh, bh, out);
}

// Round 12
// 1153.216 us; speedup vs baseline: 2.6901x; 1.1191x over previous
//
#include <hip/hip_runtime.h>

typedef __bf16 bf16x8 __attribute__((ext_vector_type(8)));
typedef unsigned short us8 __attribute__((ext_vector_type(8)));
typedef float f32x4 __attribute__((ext_vector_type(4)));

#define NROW 32      // padded rows per WG buffer (MFMA needs 16-row tiles x 2)
#define UROW 20      // useful rows per WG (256 WGs x 20 = 5120)
#define A_STR 136    // ushort stride per h row (17 dword-quads == 1 mod 8: balanced b128)
#define AX_STR 40    // ushort stride per Ax row
#define WL_STR 521   // 16B-units per frag-row of LDS Whh0 half (521 == 1 mod 8)
#define NSTEP 119

__device__ __forceinline__ unsigned short f2bf(float f){
  unsigned int x = __builtin_bit_cast(unsigned int, f);
  x += 0x7fffu + ((x >> 16) & 1u);          // RNE
  return (unsigned short)(x >> 16);
}
__device__ __forceinline__ float bf2f(unsigned short s){
  unsigned int x = ((unsigned int)s) << 16;
  return __builtin_bit_cast(float, x);
}
__device__ __forceinline__ float sigm(float x){ return 1.0f/(1.0f + __expf(-x)); }
__device__ __forceinline__ float tanh_(float x){ float e = __expf(2.0f*x); return 1.0f - 2.0f/(e + 1.0f); }

__device__ __forceinline__ f32x4 MFMA(us8 a, us8 b, f32x4 c){
  return __builtin_amdgcn_mfma_f32_16x16x32_bf16(
      __builtin_bit_cast(bf16x8, a), __builtin_bit_cast(bf16x8, b), c, 0, 0, 0);
}
// AGPR-pinned weight MFMA for layer 1 (v7/v9-proven). Layer 0 stays intrinsic
// (v11 showed asm+fences in L0 regress 15%).
__device__ __forceinline__ void mfma_ag_first(f32x4& d, us8 a, us8 b){
  asm("s_nop 1\n\tv_mfma_f32_16x16x32_bf16 %0, %1, %2, %0" : "+v"(d) : "v"(a), "a"(b));
}
__device__ __forceinline__ void mfma_ag(f32x4& d, us8 a, us8 b){
  asm("v_mfma_f32_16x16x32_bf16 %0, %1, %2, %0" : "+v"(d) : "v"(a), "a"(b));
}
__device__ __forceinline__ void accfence4(f32x4& a0, f32x4& a1, f32x4& a2, f32x4& a3){
  asm("s_nop 7\n\ts_nop 7\n\ts_nop 2"
      : "+v"(a0), "+v"(a1), "+v"(a2), "+v"(a3));
}

struct SharedMem {
  unsigned short A0[2][NROW*A_STR];     // h0 bf16, double buffered  (17408 B)
  unsigned short A1[2][NROW*A_STR];     // h1 bf16, double buffered  (17408 B)
  unsigned short Ax[2][NROW][AX_STR];   // x-MFMA A operand           (5120 B)
  unsigned short xw[512*8];             // x-MFMA B per gate-col      (8192 B)
  unsigned short W0l[8*WL_STR*8];       // Whh0 k-blocks 0,1 frags   (66688 B)
  float c_lds[2][2][512][4];            // c[layer][rt][tid][j]      (32768 B)
  float b1[512];                        //                            (2048 B)
  float Wh2f[256];                      //                            (1024 B)
  float we_s[64];
  float be_s[64];
  float bh_s[2];
};  // ~148 KB -> 1 WG/CU; 256 WGs = all 256 CUs busy

// 512 threads = 8 waves = 2/SIMD. AGPR: Wih1 64 + Whh1 64 = 128 (asm-pinned).
// Arch: WV 32 + acc 16 + transients (v9-proven split).
__global__ __launch_bounds__(512)
__attribute__((amdgpu_waves_per_eu(2, 2)))
void deepar_kernel(
    const float* __restrict__ hist, const float* __restrict__ fut,
    const float* __restrict__ We,   const float* __restrict__ be,
    const float* __restrict__ Wih0, const float* __restrict__ Whh0,
    const float* __restrict__ bih0, const float* __restrict__ bhh0,
    const float* __restrict__ Wih1, const float* __restrict__ Whh1,
    const float* __restrict__ bih1, const float* __restrict__ bhh1,
    const float* __restrict__ Wh,   const float* __restrict__ bh,
    float* __restrict__ out)
{
  __shared__ SharedMem S;
  const int tid = threadIdx.x;     // 0..511
  const int wg  = blockIdx.x;      // 0..255
  const int b   = wg >> 4;         // batch 0..15 (16 WGs per batch)
  const int n0  = (wg & 15) * UROW; // n-offset 0..300
  const int l   = tid & 63;
  const int w   = tid >> 6;        // wave 0..7
  const int gq  = l >> 4;          // k-group 0..3
  const int r   = l & 15;          // row/col within 16-tile
  const int cw  = w * 16;          // h-col base of this wave

  // ---------------- prologue ----------------
  {
    us8 z = {0,0,0,0,0,0,0,0};
    us8* pA0 = (us8*)&S.A0[0][0];
    us8* pA1 = (us8*)&S.A1[0][0];
    for (int i = tid; i < 2*NROW*A_STR/8; i += 512){ pA0[i] = z; pA1[i] = z; }
    us8* pAx = (us8*)&S.Ax[0][0][0];
    for (int i = tid; i < 2*NROW*AX_STR/8; i += 512) pAx[i] = z;
    f32x4 zf = {0.f,0.f,0.f,0.f};
    #pragma unroll
    for (int q = 0; q < 4; ++q) *(f32x4*)&S.c_lds[q >> 1][q & 1][tid][0] = zf;
  }
  if (tid < 64)       S.we_s[tid]       = We[tid];
  else if (tid < 128) S.be_s[tid - 64]  = be[tid - 64];
  else if (tid < 384) S.Wh2f[tid - 128] = Wh[tid - 128];
  else if (tid < 386) S.bh_s[tid - 384] = bh[tid - 384];
  __syncthreads();

  // per-col x weights: u = Wih0[:,:64]@We ; v = ..@be + bih0 + bhh0
  {
    const float* wr = Wih0 + tid * 68;
    float u = 0.f, v = 0.f;
    #pragma unroll 8
    for (int e = 0; e < 64; ++e){
      float wv = wr[e];
      u = fmaf(wv, S.we_s[e], u);
      v = fmaf(wv, S.be_s[e], v);
    }
    v += bih0[tid] + bhh0[tid];
    unsigned short* xp = &S.xw[tid * 8];
    xp[0] = f2bf(u);
    xp[1] = f2bf(wr[64]); xp[2] = f2bf(wr[65]); xp[3] = f2bf(wr[66]); xp[4] = f2bf(wr[67]);
    xp[5] = f2bf(v);
    xp[6] = 0; xp[7] = 0;
    S.b1[tid] = bih1[tid] + bhh1[tid];
  }
  // Whh0 k-blocks 0,1 -> LDS frags
  for (int idx = tid; idx < 8*512; idx += 512){
    int qgq = idx >> 9, col = idx & 511;
    const float* p = Whh0 + col*128 + qgq*8;
    f32x4 x0 = *(const f32x4*)p;
    f32x4 x1 = *(const f32x4*)(p + 4);
    us8 tt;
    tt[0]=f2bf(x0[0]); tt[1]=f2bf(x0[1]); tt[2]=f2bf(x0[2]); tt[3]=f2bf(x0[3]);
    tt[4]=f2bf(x1[0]); tt[5]=f2bf(x1[1]); tt[6]=f2bf(x1[2]); tt[7]=f2bf(x1[3]);
    *(us8*)&S.W0l[(qgq*WL_STR + col)*8] = tt;
  }
  // Ax constant-one column (k=5), both buffers
  if (tid < 64){ int row = tid >> 1, bsel = tid & 1; S.Ax[bsel][row][5] = 0x3F80; }
  // stage step-0 scalars (rows 0..UROW-1 only; padded rows stay zero)
  if (tid < 112){
    int srow = -1, sch = 0, tau = 0;
    if (tid < UROW){ srow = tid; sch = 0; tau = 0; }
    else if (tid >= 32){ int k = tid - 32; srow = k >> 2; sch = 1 + (k & 3); tau = 1; }
    if (srow >= 0){
      const float* p = hist + ((b*96 + tau)*320 + n0 + srow)*5;
      S.Ax[0][srow][sch] = f2bf(p[sch]);
    }
  }

  // register weights (per wave, cols g*128+cw+r):
  //   WV  (arch):  Whh0 k2,k3  8 frags = 32 regs (intrinsic path)
  //   WA1 (AGPR):  Wih1 all k 16 frags = 64 regs (asm path)
  //   WA2 (AGPR):  Whh1 all k 16 frags = 64 regs (asm path)
  us8 WV[4][2], WA1[4][4], WA2[4][4];
  #pragma unroll
  for (int m = 0; m < 3; ++m){
    const float* base = (m == 0) ? Whh0 : (m == 1) ? Wih1 : Whh1;
    #pragma unroll
    for (int g = 0; g < 4; ++g){
      int col = g*128 + cw + r;
      #pragma unroll
      for (int q = 0; q < 4; ++q){
        if (m == 0 && q < 2) continue;
        const float* p = base + col*128 + q*32 + gq*8;
        f32x4 x0 = *(const f32x4*)p;
        f32x4 x1 = *(const f32x4*)(p + 4);
        us8 tt;
        tt[0]=f2bf(x0[0]); tt[1]=f2bf(x0[1]); tt[2]=f2bf(x0[2]); tt[3]=f2bf(x0[3]);
        tt[4]=f2bf(x1[0]); tt[5]=f2bf(x1[1]); tt[6]=f2bf(x1[2]); tt[7]=f2bf(x1[3]);
        if (m == 0)      WV[g][q-2] = tt;
        else if (m == 1) WA1[g][q]  = tt;
        else             WA2[g][q]  = tt;
      }
    }
  }

  __syncthreads();

  float b1g[4];
  #pragma unroll
  for (int g = 0; g < 4; ++g) b1g[g] = S.b1[g*128 + cw + r];
  const float bh0 = S.bh_s[0], bh1 = S.bh_s[1];

  // ---------------- time loop ----------------
  for (int t = 0; t < NSTEP; ++t){
    const int pb = t & 1, nb = pb ^ 1;
    const unsigned short* A0r = S.A0[pb];
    unsigned short*       A0w = S.A0[nb];
    const unsigned short* A1r = S.A1[pb];
    unsigned short*       A1w = S.A1[nb];

    // prefetch next-step scalars (latency hidden under both layers)
    float stv = 0.f; int sto = -1;
    if (t + 1 < NSTEP && tid < 112){
      int srow = -1, sch = 0, tau = 0;
      if (tid < UROW){ srow = tid; sch = 0; tau = t + 1; }
      else if (tid >= 32){ int k = tid - 32; srow = k >> 2; sch = 1 + (k & 3); tau = t + 2; }
      if (srow >= 0){
        const float* p = (tau < 96) ? (hist + ((b*96 + tau)*320 + n0 + srow)*5)
                                    : (fut  + ((b*24 + (tau - 96))*320 + n0 + srow)*5);
        stv = p[sch];
        sto = nb*NROW*AX_STR + srow*AX_STR + sch;
      }
    }

    // ---- layer 0 (intrinsic): gates = x-MFMA + h0 @ Whh0^T (k0,k1 LDS; k2,k3 regs) ----
    #pragma unroll
    for (int rt = 0; rt < 2; ++rt){
      const int rbase = rt * 16;
      f32x4 cprev = *(const f32x4*)&S.c_lds[0][rt][tid][0];
      f32x4 acc[4];
      us8 ax = *(const us8*)&S.Ax[pb][rbase + r][gq*8];
      #pragma unroll
      for (int g = 0; g < 4; ++g){
        us8 bx = *(const us8*)&S.xw[(g*128 + cw + r)*8];
        f32x4 z = {0.f,0.f,0.f,0.f};
        acc[g] = MFMA(ax, bx, z);
      }
      #pragma unroll
      for (int q = 0; q < 2; ++q){
        us8 a = *(const us8*)&A0r[(rbase + r)*A_STR + q*32 + gq*8];
        #pragma unroll
        for (int g = 0; g < 4; ++g){
          us8 bw = *(const us8*)&S.W0l[((q*4 + gq)*WL_STR + g*128 + cw + r)*8];
          acc[g] = MFMA(a, bw, acc[g]);
        }
      }
      #pragma unroll
      for (int q = 2; q < 4; ++q){
        us8 a = *(const us8*)&A0r[(rbase + r)*A_STR + q*32 + gq*8];
        #pragma unroll
        for (int g = 0; g < 4; ++g)
          acc[g] = MFMA(a, WV[g][q-2], acc[g]);
      }
      f32x4 cnew;
      #pragma unroll
      for (int j = 0; j < 4; ++j){
        float c = fmaf(sigm(acc[1][j]), cprev[j], sigm(acc[0][j]) * tanh_(acc[2][j]));
        cnew[j] = c;
        float h = sigm(acc[3][j]) * tanh_(c);
        A0w[(rbase + gq*4 + j)*A_STR + cw + r] = f2bf(h);
      }
      *(f32x4*)&S.c_lds[0][rt][tid][0] = cnew;
    }
    __syncthreads();   // B1: new h0 visible

    // ---- layer 1 (AGPR asm): gates = b1 + h0new @ Wih1^T + h1 @ Whh1^T ----
    #pragma unroll
    for (int rt = 0; rt < 2; ++rt){
      const int rbase = rt * 16;
      f32x4 cprev = *(const f32x4*)&S.c_lds[1][rt][tid][0];
      f32x4 acc[4];
      #pragma unroll
      for (int g = 0; g < 4; ++g){
        f32x4 iv = {b1g[g], b1g[g], b1g[g], b1g[g]};
        acc[g] = iv;
      }
      {
        us8 a = *(const us8*)&A0w[(rbase + r)*A_STR + 0*32 + gq*8];
        mfma_ag_first(acc[0], a, WA1[0][0]);
        mfma_ag(acc[1], a, WA1[1][0]);
        mfma_ag(acc[2], a, WA1[2][0]);
        mfma_ag(acc[3], a, WA1[3][0]);
      }
      #pragma unroll
      for (int q = 1; q < 4; ++q){
        us8 a = *(const us8*)&A0w[(rbase + r)*A_STR + q*32 + gq*8];
        #pragma unroll
        for (int g = 0; g < 4; ++g) mfma_ag(acc[g], a, WA1[g][q]);
      }
      #pragma unroll
      for (int q = 0; q < 4; ++q){
        us8 a = *(const us8*)&A1r[(rbase + r)*A_STR + q*32 + gq*8];
        #pragma unroll
        for (int g = 0; g < 4; ++g) mfma_ag(acc[g], a, WA2[g][q]);
      }
      accfence4(acc[0], acc[1], acc[2], acc[3]);
      f32x4 cnew;
      #pragma unroll
      for (int j = 0; j < 4; ++j){
        float c = fmaf(sigm(acc[1][j]), cprev[j], sigm(acc[0][j]) * tanh_(acc[2][j]));
        cnew[j] = c;
        float h = sigm(acc[3][j]) * tanh_(c);
        A1w[(rbase + gq*4 + j)*A_STR + cw + r] = f2bf(h);
      }
      *(f32x4*)&S.c_lds[1][rt][tid][0] = cnew;
    }
    if (sto >= 0) ((unsigned short*)&S.Ax[0][0][0])[sto] = f2bf(stv);
    __syncthreads();   // B2: new h1 + next-step Ax visible

    // ---- head (last 24 steps): barrier-free shfl-xor reduce over 16 cg lanes ----
    if (t >= 95){
      const int rown = tid >> 4, cg = tid & 15;
      if (rown < UROW){
        us8 hv = *(const us8*)&A1w[rown*A_STR + cg*8];
        f32x4 wA0v = *(const f32x4*)&S.Wh2f[cg*8];
        f32x4 wA1v = *(const f32x4*)&S.Wh2f[cg*8 + 4];
        f32x4 wB0v = *(const f32x4*)&S.Wh2f[128 + cg*8];
        f32x4 wB1v = *(const f32x4*)&S.Wh2f[128 + cg*8 + 4];
        float pm = 0.f, ps = 0.f;
        #pragma unroll
        for (int k = 0; k < 4; ++k){
          float h0v = bf2f(hv[k]);     h0v = h0v > 0.f ? h0v : 0.f;
          float h1v = bf2f(hv[4 + k]); h1v = h1v > 0.f ? h1v : 0.f;
          pm = fmaf(h0v, wA0v[k], pm);  pm = fmaf(h1v, wA1v[k], pm);
          ps = fmaf(h0v, wB0v[k], ps);  ps = fmaf(h1v, wB1v[k], ps);
        }
        #pragma unroll
        for (int m = 1; m < 16; m <<= 1){
          pm += __shfl_xor(pm, m, 64);
          ps += __shfl_xor(ps, m, 64);
        }
        if (cg == 0){
          float mu = pm + bh0;
          float sg = ps + bh1;
          sg = (sg > 15.f) ? sg : __logf(1.0f + __expf(sg));
          float2 o2 = make_float2(mu, sg);
          *(float2*)&out[((b*24 + (t - 95))*320 + (n0 + rown))*2] = o2;
        }
      }
    }
  }
}

extern "C" void kernel_launch(void* const* d_in, const int* in_sizes, int n_in,
                              void* d_out, int out_size, void* d_ws, size_t ws_size,
                              hipStream_t stream) {
  const float* hist = (const float*)d_in[0];
  const float* fut  = (const float*)d_in[1];
  const float* We   = (const float*)d_in[2];
  const float* be   = (const float*)d_in[3];
  const float* Wih0 = (const float*)d_in[4];
  const float* Whh0 = (const float*)d_in[5];
  const float* bih0 = (const float*)d_in[6];
  const float* bhh0 = (const float*)d_in[7];
  const float* Wih1 = (const float*)d_in[8];
  const float* Whh1 = (const float*)d_in[9];
  const float* bih1 = (const float*)d_in[10];
  const float* bhh1 = (const float*)d_in[11];
  const float* Wh   = (const float*)d_in[12];
  const float* bh   = (const float*)d_in[13];
  float* out = (float*)d_out;

  deepar_kernel<<<dim3(256), dim3(512), 0, stream>>>(
      hist, fut, We, be, Wih0, Whh0, bih0, bhh0,
      Wih1, Whh1, bih1, bhh1, Wh, bh, out);
}